// Round 13
// baseline (167.701 us; speedup 1.0000x reference)
//
#include <hip/hip_runtime.h>
#include <math.h>

#define NE 64
#define NTASK 6
#define BLK 256
#define RPI 32      // rows per wave (2 halves of 16; 4 lanes per row)

// ---------------------------------------------------------------------------
// Kernel A: per-task precompute (6 x 64 tables) in f64, weights staged in LDS.
// Outputs: tab_f (f32 {cl,ns} pairs, XOR-swizzled 16B granularity), tab_d
// (double2 [t*64+e]). Also zeroes `load`.  (unchanged from R11/R12)
// ---------------------------------------------------------------------------
__global__ void precompute_kernel(
    const float* __restrict__ embed_table,   // (6,32)
    const float* __restrict__ expert_keys,   // (32,32)
    const float* __restrict__ in_proj_w,     // (96,32)
    const float* __restrict__ in_proj_b,     // (96,)
    const float* __restrict__ fc_gate_w,     // (64,32)
    const float* __restrict__ fc_gate_b,     // (64,)
    const float* __restrict__ fc_noise_w,    // (64,32)
    const float* __restrict__ fc_noise_b,    // (64,)
    float*   __restrict__ tab_f,             // 1024 floats (swizzled float4s)
    double2* __restrict__ tab_d,             // 512 double2 [t*64+e]
    float*   __restrict__ load)              // (64,) zero-init
{
    __shared__ float s_win[96 * 32];
    __shared__ float s_wg[64 * 32];
    __shared__ float s_wn[64 * 32];
    __shared__ float s_keys[32 * 32];
    __shared__ float s_emb[6 * 32];
    __shared__ float s_bin[96], s_bg[64], s_bn[64];
    __shared__ double Ksh[32][32];
    __shared__ double Qsh[6][32];
    __shared__ double sc[24][32];
    __shared__ double attn[6][32];
    __shared__ double ew[6][32];
    __shared__ double red[24];
    __shared__ double red2[6];
    const int tid = threadIdx.x;

    if (tid < NE) load[tid] = 0.f;

    for (int i = tid; i < 96 * 32; i += BLK) s_win[i] = in_proj_w[i];
    for (int i = tid; i < 64 * 32; i += BLK) { s_wg[i] = fc_gate_w[i]; s_wn[i] = fc_noise_w[i]; }
    for (int i = tid; i < 32 * 32; i += BLK) s_keys[i] = expert_keys[i];
    for (int i = tid; i < 6 * 32;  i += BLK) s_emb[i] = embed_table[i];
    if (tid < 96) s_bin[tid] = in_proj_b[tid];
    if (tid < 64) { s_bg[tid] = fc_gate_b[tid]; s_bn[tid] = fc_noise_b[tid]; }
    __syncthreads();

    for (int idx = tid; idx < 32 * 32; idx += BLK) {
        int s = idx >> 5, j = idx & 31;
        double acc = (double)s_bin[32 + j];
        for (int d = 0; d < 32; ++d)
            acc += (double)s_keys[s * 32 + d] * (double)s_win[(32 + j) * 32 + d];
        Ksh[s][j] = acc;
    }
    for (int idx = tid; idx < NTASK * 32; idx += BLK) {
        int t = idx >> 5, j = idx & 31;
        double acc = (double)s_bin[j];
        for (int d = 0; d < 32; ++d)
            acc += (double)s_emb[t * 32 + d] * (double)s_win[j * 32 + d];
        Qsh[t][j] = acc;
    }
    __syncthreads();

    const double SCALE = 1.0 / (double)((float)2.8284271247461903);
    for (int idx = tid; idx < 24 * 32; idx += BLK) {
        int th = idx >> 5, s = idx & 31;
        int t = th >> 2, h = th & 3;
        double acc = 0.0;
        for (int d = 0; d < 8; ++d)
            acc += Qsh[t][h * 8 + d] * Ksh[s][h * 8 + d];
        sc[th][s] = acc * SCALE;
    }
    __syncthreads();
    if (tid < 24) {
        double m = sc[tid][0];
        for (int s = 1; s < 32; ++s) m = fmax(m, sc[tid][s]);
        red[tid] = m;
    }
    __syncthreads();
    for (int idx = tid; idx < 24 * 32; idx += BLK) {
        int th = idx >> 5, s = idx & 31;
        sc[th][s] = exp(sc[th][s] - red[th]);
    }
    __syncthreads();
    if (tid < 24) {
        double sum = 0.0;
        for (int s = 0; s < 32; ++s) sum += sc[tid][s];
        red[tid] = 1.0 / sum;
    }
    __syncthreads();
    for (int idx = tid; idx < NTASK * 32; idx += BLK) {
        int t = idx >> 5, s = idx & 31;
        attn[t][s] = 0.25 * (sc[t*4+0][s]*red[t*4+0] + sc[t*4+1][s]*red[t*4+1]
                           + sc[t*4+2][s]*red[t*4+2] + sc[t*4+3][s]*red[t*4+3]);
    }
    __syncthreads();
    if (tid < NTASK) {
        double m = attn[tid][0];
        for (int s = 1; s < 32; ++s) m = fmax(m, attn[tid][s]);
        red2[tid] = m;
    }
    __syncthreads();
    for (int idx = tid; idx < NTASK * 32; idx += BLK) {
        int t = idx >> 5, s = idx & 31;
        ew[t][s] = exp(attn[t][s] - red2[t]);
    }
    __syncthreads();
    if (tid < NTASK) {
        double sum = 0.0;
        for (int s = 0; s < 32; ++s) sum += ew[tid][s];
        red2[tid] = 1.0 / sum;
    }
    __syncthreads();

    {
        float2* tab_f2 = (float2*)tab_f;
        for (int idx = tid; idx < NTASK * NE; idx += BLK) {
            int t = idx >> 6, e = idx & 63;
            double inv = red2[t];
            double a  = (double)s_bg[e];
            double n0 = (double)s_bn[e];
            for (int d = 0; d < 32; ++d) {
                double w = ew[t][d] * inv;
                a  += w * (double)s_wg[e * 32 + d];
                n0 += w * (double)s_wn[e * 32 + d];
            }
            double sp = (n0 > 0.0) ? (n0 + log1p(exp(-n0))) : log1p(exp(n0));
            double ns = sp + 0.01;
            const int p  = e >> 1;
            const int cc = (p >> 3) & 3, rr = p & 7;
            const int i4 = t * 32 + p;
            const int dst = (i4 & ~7) | (rr ^ ((2 * cc + t) & 7));
            tab_f2[dst * 2 + (e & 1)] = make_float2((float)a, (float)ns);
            tab_d[t * 64 + e] = make_double2(a, ns);
        }
        for (int idx = NTASK * NE + tid; idx < 512; idx += BLK) {
            tab_f2[idx] = make_float2(0.f, 0.f);
        }
    }
}

// ---------------------------------------------------------------------------
// Kernel B: ONE-SHOT waves. Global wave id == 32-row group id. No loop, no
// double-buffer: issue 8 contiguous 1KB loads immediately, stage tables,
// sync, LDS-bounce redistribute, top-2 scan + f64 refine, contiguous
// shuffle-gathered stores, exit. TLP from wave turnover hides all latency.
// ---------------------------------------------------------------------------
__global__ __launch_bounds__(BLK) void router_kernel(
    const int*     __restrict__ taskID,
    const float4*  __restrict__ noise4,   // (B*16)
    const float4*  __restrict__ tabf4,    // 256 float4 (swizzled)
    const double2* __restrict__ tabd,     // 512
    float4* __restrict__ gates4,          // (B*16)
    float*  __restrict__ load,            // (64,)
    int B)
{
    __shared__ float4  s_tabf4[256];        // 4 KB
    __shared__ double2 s_tabd[512];         // 8 KB
    __shared__ float   s_load[NE];
    __shared__ float4  s_stage[BLK/64][256]; // 16 KB (4KB per wave)

    const int tid  = threadIdx.x;
    const int lane = tid & 63;
    const int wid  = tid >> 6;
    const int sub  = lane >> 2;
    const int c    = lane & 3;
    const int ebase = c * 16;
    const int W = blockIdx.x * (BLK / 64) + wid;   // global wave id = group id
    const int nGroup = (B + RPI - 1) / RPI;
    const int n4 = B * 16;
    const float4 zero4 = make_float4(0.f, 0.f, 0.f, 0.f);
    const bool active = W < nGroup;

    // ---- issue this wave's noise + taskID loads FIRST (latency overlaps
    //      the table staging below; compiler defers waitcnt to first use) ----
    float4 cur[8];
    int tA = 0, tB = 0;
    {
        const int gb = W * 512;
        #pragma unroll
        for (int j = 0; j < 8; ++j) {
            const int idx = gb + j * 64 + lane;
            cur[j] = (active && idx < n4) ? noise4[idx] : zero4;
        }
        const int rA = W * RPI + sub, rB = rA + 16;
        tA = (active && rA < B) ? taskID[rA] : 0;
        tB = (active && rB < B) ? taskID[rB] : 0;
    }

    // ---- stage tables (L2-hot after first blocks) ----
    for (int i = tid; i < 256; i += BLK) s_tabf4[i] = tabf4[i];
    for (int i = tid; i < 512; i += BLK) s_tabd[i] = tabd[i];
    if (tid < NE) s_load[tid] = 0.f;
    __syncthreads();

#define INS2(l_, e_, n_) {                                                     \
        const bool b1_ = (l_) > v1, b2_ = (l_) > v2;                           \
        v2 = b1_ ? v1 : (b2_ ? (l_) : v2);                                     \
        i2 = b1_ ? i1 : (b2_ ? (e_) : i2);                                     \
        n2 = b1_ ? n1 : (b2_ ? (n_) : n2);                                     \
        v1 = b1_ ? (l_) : v1;                                                  \
        i1 = b1_ ? (e_) : i1;                                                  \
        n1 = b1_ ? (n_) : n1; }

#define STEP(r_, nlo_, nhi_) {                                                 \
        const float4 tv = s_tabf4[tb + ((r_) ^ x)];                            \
        const float l0 = __fadd_rn(tv.x, __fmul_rn((nlo_), tv.y));             \
        const float l1 = __fadd_rn(tv.z, __fmul_rn((nhi_), tv.w));             \
        INS2(l0, ebase + 2 * (r_),     (nlo_));                                \
        INS2(l1, ebase + 2 * (r_) + 1, (nhi_)); }

#define PROCHALF(t_, rowbase_, cj0, cj1, cj2, cj3)                             \
    {                                                                          \
        _Pragma("unroll")                                                      \
        for (int j = 0; j < 4; ++j) {                                          \
            const float4 vsrc = (j == 0) ? (cj0) : (j == 1) ? (cj1)            \
                              : (j == 2) ? (cj2) : (cj3);                      \
            const int f  = j * 64 + lane;                                      \
            const int rl = f >> 4, q = f & 15;                                 \
            s_stage[wid][rl * 16 + (q ^ rl)] = vsrc;                           \
        }                                                                      \
        float4 z[4];                                                           \
        _Pragma("unroll")                                                      \
        for (int k = 0; k < 4; ++k)                                            \
            z[k] = s_stage[wid][sub * 16 + ((c * 4 + k) ^ sub)];               \
        const int t  = (t_);                                                   \
        const int x  = (2 * c + t) & 7;                                        \
        const int tb = t * 32 + c * 8;                                         \
        float v1 = -INFINITY, v2 = -INFINITY;                                  \
        int   i1 = 0, i2 = 0;                                                  \
        float n1 = 0.f, n2 = 0.f;                                              \
        STEP(0, z[0].x, z[0].y); STEP(1, z[0].z, z[0].w);                      \
        STEP(2, z[1].x, z[1].y); STEP(3, z[1].z, z[1].w);                      \
        STEP(4, z[2].x, z[2].y); STEP(5, z[2].z, z[2].w);                      \
        STEP(6, z[3].x, z[3].y); STEP(7, z[3].z, z[3].w);                      \
        _Pragma("unroll")                                                      \
        for (int m = 1; m <= 2; m <<= 1) {                                     \
            const float w1 = __shfl_xor(v1, m), w2 = __shfl_xor(v2, m);        \
            const int   j1 = __shfl_xor(i1, m), j2 = __shfl_xor(i2, m);        \
            const float q1 = __shfl_xor(n1, m), q2 = __shfl_xor(n2, m);        \
            const bool aw = (v1 > w1) || (v1 == w1 && i1 < j1);                \
            const float p1 = aw ? v1 : w1, p2 = aw ? v2 : w2;                  \
            const int   pi1 = aw ? i1 : j1, pi2 = aw ? i2 : j2;                \
            const float pn1 = aw ? n1 : q1, pn2 = aw ? n2 : q2;                \
            const float u1 = aw ? w1 : v1;                                     \
            const int   ui1 = aw ? j1 : i1;                                    \
            const float un1 = aw ? q1 : n1;                                    \
            const bool b2 = (p2 > u1) || (p2 == u1 && pi2 < ui1);              \
            v1 = p1;  i1 = pi1; n1 = pn1;                                      \
            v2 = b2 ? p2 : u1;  i2 = b2 ? pi2 : ui1;  n2 = b2 ? pn2 : un1;     \
        }                                                                      \
        const double2 A  = s_tabd[t * 64 + i1];                                \
        const double2 Bt = s_tabd[t * 64 + i2];                                \
        double da = A.x  + (double)n1 * A.y;  int ia = i1;                     \
        double db = Bt.x + (double)n2 * Bt.y; int ib = i2;                     \
        if (db > da || (db == da && ib < ia)) {                                \
            double tv_ = da; da = db; db = tv_;                                \
            int ti_ = ia; ia = ib; ib = ti_;                                   \
        }                                                                      \
        const float e2 = expf((float)(db - da));                               \
        const float g1 = 1.0f / (1.0f + e2);                                   \
        const float g2 = e2 / (1.0f + e2);                                     \
        const int iab = ia | (ib << 8);                                        \
        if (c == 0 && ((rowbase_) + sub) < B) {                                \
            atomicAdd(&s_load[ia], g1);                                        \
            atomicAdd(&s_load[ib], g2);                                        \
        }                                                                      \
        const int gb_ = (rowbase_) * 16;                                       \
        _Pragma("unroll")                                                      \
        for (int j = 0; j < 4; ++j) {                                          \
            const int f  = j * 64 + lane;                                      \
            const int rr = f >> 4;                                             \
            const int p  = f & 15;                                             \
            const int src = rr << 2;                                           \
            const int   siab = __shfl(iab, src);                               \
            const float sg1  = __shfl(g1,  src);                               \
            const float sg2  = __shfl(g2,  src);                               \
            const int sia = siab & 255, sib = siab >> 8;                       \
            const int e0 = p * 4;                                              \
            float4 w;                                                          \
            w.x = (e0 + 0 == sia) ? sg1 : ((e0 + 0 == sib) ? sg2 : 0.f);       \
            w.y = (e0 + 1 == sia) ? sg1 : ((e0 + 1 == sib) ? sg2 : 0.f);       \
            w.z = (e0 + 2 == sia) ? sg1 : ((e0 + 2 == sib) ? sg2 : 0.f);       \
            w.w = (e0 + 3 == sia) ? sg1 : ((e0 + 3 == sib) ? sg2 : 0.f);       \
            const int gidx = gb_ + f;                                          \
            if (gidx < n4) gates4[gidx] = w;                                   \
        }                                                                      \
    }

    if (active) {
        PROCHALF(tA, W * RPI,      cur[0], cur[1], cur[2], cur[3])
        PROCHALF(tB, W * RPI + 16, cur[4], cur[5], cur[6], cur[7])
    }

#undef PROCHALF
#undef STEP
#undef INS2

    __syncthreads();
    if (tid < NE) atomicAdd(&load[tid], s_load[tid]);
}

// ---------------------------------------------------------------------------
extern "C" void kernel_launch(void* const* d_in, const int* in_sizes, int n_in,
                              void* d_out, int out_size, void* d_ws, size_t ws_size,
                              hipStream_t stream) {
    const int*   taskID      = (const int*)  d_in[0];
    const float* embed_table = (const float*)d_in[1];
    const float* expert_keys = (const float*)d_in[2];
    const float* in_proj_w   = (const float*)d_in[3];
    const float* in_proj_b   = (const float*)d_in[4];
    const float* fc_gate_w   = (const float*)d_in[5];
    const float* fc_gate_b   = (const float*)d_in[6];
    const float* fc_noise_w  = (const float*)d_in[7];
    const float* fc_noise_b  = (const float*)d_in[8];
    const float* noise       = (const float*)d_in[9];

    const int B = in_sizes[0];

    float*   tab_f = (float*)d_ws;                    // 4 KB
    double2* tab_d = (double2*)((char*)d_ws + 4096);  // 8 KB

    float* gates = (float*)d_out;
    float* load  = gates + (size_t)B * NE;

    precompute_kernel<<<1, BLK, 0, stream>>>(embed_table, expert_keys, in_proj_w, in_proj_b,
                                             fc_gate_w, fc_gate_b, fc_noise_w, fc_noise_b,
                                             tab_f, tab_d, load);

    const int nGroup = (B + RPI - 1) / RPI;
    const int grid   = (nGroup + (BLK / 64) - 1) / (BLK / 64);
    router_kernel<<<grid, BLK, 0, stream>>>(taskID, (const float4*)noise,
                                            (const float4*)tab_f, tab_d,
                                            (float4*)gates, load, B);
}

// Round 14
// 115.092 us; speedup vs baseline: 1.4571x; 1.4571x over previous
//
#include <hip/hip_runtime.h>
#include <math.h>

#define NE 64
#define NTASK 6
#define BLK 256
#define GRID 1280
#define RPI 32      // rows per wave-iteration (2 halves of 16; 4 lanes per row)

// ---------------------------------------------------------------------------
// Kernel A: per-task precompute (6 x 64 tables) in f64 internally, f32 output.
// tab_f: f32 {cl,ns} pairs, XOR-swizzled at 16B granularity for the router's
// conflict-free per-team reads. Also zeroes `load`.
// ---------------------------------------------------------------------------
__global__ void precompute_kernel(
    const float* __restrict__ embed_table,   // (6,32)
    const float* __restrict__ expert_keys,   // (32,32)
    const float* __restrict__ in_proj_w,     // (96,32)
    const float* __restrict__ in_proj_b,     // (96,)
    const float* __restrict__ fc_gate_w,     // (64,32)
    const float* __restrict__ fc_gate_b,     // (64,)
    const float* __restrict__ fc_noise_w,    // (64,32)
    const float* __restrict__ fc_noise_b,    // (64,)
    float*   __restrict__ tab_f,             // 1024 floats (swizzled float4s)
    float*   __restrict__ load)              // (64,) zero-init
{
    __shared__ float s_win[96 * 32];
    __shared__ float s_wg[64 * 32];
    __shared__ float s_wn[64 * 32];
    __shared__ float s_keys[32 * 32];
    __shared__ float s_emb[6 * 32];
    __shared__ float s_bin[96], s_bg[64], s_bn[64];
    __shared__ double Ksh[32][32];
    __shared__ double Qsh[6][32];
    __shared__ double sc[24][32];
    __shared__ double attn[6][32];
    __shared__ double ew[6][32];
    __shared__ double red[24];
    __shared__ double red2[6];
    const int tid = threadIdx.x;

    if (tid < NE) load[tid] = 0.f;

    for (int i = tid; i < 96 * 32; i += BLK) s_win[i] = in_proj_w[i];
    for (int i = tid; i < 64 * 32; i += BLK) { s_wg[i] = fc_gate_w[i]; s_wn[i] = fc_noise_w[i]; }
    for (int i = tid; i < 32 * 32; i += BLK) s_keys[i] = expert_keys[i];
    for (int i = tid; i < 6 * 32;  i += BLK) s_emb[i] = embed_table[i];
    if (tid < 96) s_bin[tid] = in_proj_b[tid];
    if (tid < 64) { s_bg[tid] = fc_gate_b[tid]; s_bn[tid] = fc_noise_b[tid]; }
    __syncthreads();

    for (int idx = tid; idx < 32 * 32; idx += BLK) {
        int s = idx >> 5, j = idx & 31;
        double acc = (double)s_bin[32 + j];
        for (int d = 0; d < 32; ++d)
            acc += (double)s_keys[s * 32 + d] * (double)s_win[(32 + j) * 32 + d];
        Ksh[s][j] = acc;
    }
    for (int idx = tid; idx < NTASK * 32; idx += BLK) {
        int t = idx >> 5, j = idx & 31;
        double acc = (double)s_bin[j];
        for (int d = 0; d < 32; ++d)
            acc += (double)s_emb[t * 32 + d] * (double)s_win[j * 32 + d];
        Qsh[t][j] = acc;
    }
    __syncthreads();

    const double SCALE = 1.0 / (double)((float)2.8284271247461903);
    for (int idx = tid; idx < 24 * 32; idx += BLK) {
        int th = idx >> 5, s = idx & 31;
        int t = th >> 2, h = th & 3;
        double acc = 0.0;
        for (int d = 0; d < 8; ++d)
            acc += Qsh[t][h * 8 + d] * Ksh[s][h * 8 + d];
        sc[th][s] = acc * SCALE;
    }
    __syncthreads();
    if (tid < 24) {
        double m = sc[tid][0];
        for (int s = 1; s < 32; ++s) m = fmax(m, sc[tid][s]);
        red[tid] = m;
    }
    __syncthreads();
    for (int idx = tid; idx < 24 * 32; idx += BLK) {
        int th = idx >> 5, s = idx & 31;
        sc[th][s] = exp(sc[th][s] - red[th]);
    }
    __syncthreads();
    if (tid < 24) {
        double sum = 0.0;
        for (int s = 0; s < 32; ++s) sum += sc[tid][s];
        red[tid] = 1.0 / sum;
    }
    __syncthreads();
    for (int idx = tid; idx < NTASK * 32; idx += BLK) {
        int t = idx >> 5, s = idx & 31;
        attn[t][s] = 0.25 * (sc[t*4+0][s]*red[t*4+0] + sc[t*4+1][s]*red[t*4+1]
                           + sc[t*4+2][s]*red[t*4+2] + sc[t*4+3][s]*red[t*4+3]);
    }
    __syncthreads();
    if (tid < NTASK) {
        double m = attn[tid][0];
        for (int s = 1; s < 32; ++s) m = fmax(m, attn[tid][s]);
        red2[tid] = m;
    }
    __syncthreads();
    for (int idx = tid; idx < NTASK * 32; idx += BLK) {
        int t = idx >> 5, s = idx & 31;
        ew[t][s] = exp(attn[t][s] - red2[t]);
    }
    __syncthreads();
    if (tid < NTASK) {
        double sum = 0.0;
        for (int s = 0; s < 32; ++s) sum += ew[tid][s];
        red2[tid] = 1.0 / sum;
    }
    __syncthreads();

    {
        float2* tab_f2 = (float2*)tab_f;
        for (int idx = tid; idx < NTASK * NE; idx += BLK) {
            int t = idx >> 6, e = idx & 63;
            double inv = red2[t];
            double a  = (double)s_bg[e];
            double n0 = (double)s_bn[e];
            for (int d = 0; d < 32; ++d) {
                double w = ew[t][d] * inv;
                a  += w * (double)s_wg[e * 32 + d];
                n0 += w * (double)s_wn[e * 32 + d];
            }
            double sp = (n0 > 0.0) ? (n0 + log1p(exp(-n0))) : log1p(exp(n0));
            double ns = sp + 0.01;
            const int p  = e >> 1;
            const int cc = (p >> 3) & 3, rr = p & 7;
            const int i4 = t * 32 + p;
            const int dst = (i4 & ~7) | (rr ^ ((2 * cc + t) & 7));
            tab_f2[dst * 2 + (e & 1)] = make_float2((float)a, (float)ns);
        }
        for (int idx = NTASK * NE + tid; idx < 512; idx += BLK) {
            tab_f2[idx] = make_float2(0.f, 0.f);
        }
    }
}

// ---------------------------------------------------------------------------
// Kernel B: all-f32 routing. Contiguous loads + LDS bounce (as R12), TWO
// independent 8-expert cascades merged in-lane, 2 shuffle-merge rounds,
// f32 softmax, contiguous shuffle-gathered stores. No f64 anywhere.
// ---------------------------------------------------------------------------
__global__ __launch_bounds__(BLK) void router_kernel(
    const int*     __restrict__ taskID,
    const float4*  __restrict__ noise4,   // (B*16)
    const float4*  __restrict__ tabf4,    // 256 float4 (swizzled)
    float4* __restrict__ gates4,          // (B*16)
    float*  __restrict__ load,            // (64,)
    int B)
{
    __shared__ float4 s_tabf4[256];         // 4 KB
    __shared__ float  s_load[NE];
    __shared__ float4 s_stage[BLK/64][256]; // 16 KB (4KB per wave)

    const int tid = threadIdx.x;
    for (int i = tid; i < 256; i += BLK) s_tabf4[i] = tabf4[i];
    if (tid < NE) s_load[tid] = 0.f;
    __syncthreads();

    const int lane  = tid & 63;
    const int wid   = tid >> 6;
    const int sub   = lane >> 2;
    const int c     = lane & 3;
    const int ebase = c * 16;
    const int W = (blockIdx.x * BLK + tid) >> 6;
    const int nWaves = GRID * (BLK / 64);
    const int nGroup = (B + RPI - 1) / RPI;
    const int n4 = B * 16;
    const float4 zero4 = make_float4(0.f, 0.f, 0.f, 0.f);

    float4 cur[8], nxt[8];
    int tA = 0, tB = 0;

    {
        const int gb = W * 512;
        #pragma unroll
        for (int j = 0; j < 8; ++j) {
            const int idx = gb + j * 64 + lane;
            cur[j] = (W < nGroup && idx < n4) ? noise4[idx] : zero4;
        }
        const int rA = W * RPI + sub, rB = rA + 16;
        tA = (W < nGroup && rA < B) ? taskID[rA] : 0;
        tB = (W < nGroup && rB < B) ? taskID[rB] : 0;
    }

    for (int g = W; g < nGroup; g += nWaves) {
        const int gn = g + nWaves;
        {
            const int gb = gn * 512;
            #pragma unroll
            for (int j = 0; j < 8; ++j) {
                const int idx = gb + j * 64 + lane;
                nxt[j] = (gn < nGroup && idx < n4) ? noise4[idx] : zero4;
            }
        }
        int ntA = 0, ntB = 0;
        {
            const int rA = gn * RPI + sub, rB = rA + 16;
            ntA = (gn < nGroup && rA < B) ? taskID[rA] : 0;
            ntB = (gn < nGroup && rB < B) ? taskID[rB] : 0;
        }

// top-2 insert into chain (vX1,iX1,nX1,vX2,iX2,nX2)
#define INS2C(V1,I1,N1,V2,I2,N2, l_, e_, n_) {                                 \
        const bool b1_ = (l_) > V1, b2_ = (l_) > V2;                           \
        V2 = b1_ ? V1 : (b2_ ? (l_) : V2);                                     \
        I2 = b1_ ? I1 : (b2_ ? (e_) : I2);                                     \
        N2 = b1_ ? N1 : (b2_ ? (n_) : N2);                                     \
        V1 = b1_ ? (l_) : V1;                                                  \
        I1 = b1_ ? (e_) : I1;                                                  \
        N1 = b1_ ? (n_) : N1; }

#define STEPC(V1,I1,N1,V2,I2,N2, r_, nlo_, nhi_) {                             \
        const float4 tv = s_tabf4[tb + ((r_) ^ x)];                            \
        const float l0 = __fadd_rn(tv.x, __fmul_rn((nlo_), tv.y));             \
        const float l1 = __fadd_rn(tv.z, __fmul_rn((nhi_), tv.w));             \
        INS2C(V1,I1,N1,V2,I2,N2, l0, ebase + 2 * (r_),     (nlo_));            \
        INS2C(V1,I1,N1,V2,I2,N2, l1, ebase + 2 * (r_) + 1, (nhi_)); }

#define PROCHALF(t_, rowbase_, cj0, cj1, cj2, cj3)                             \
    {                                                                          \
        _Pragma("unroll")                                                      \
        for (int j = 0; j < 4; ++j) {                                          \
            const float4 vsrc = (j == 0) ? (cj0) : (j == 1) ? (cj1)            \
                              : (j == 2) ? (cj2) : (cj3);                      \
            const int f  = j * 64 + lane;                                      \
            const int rl = f >> 4, q = f & 15;                                 \
            s_stage[wid][rl * 16 + (q ^ rl)] = vsrc;                           \
        }                                                                      \
        float4 z[4];                                                           \
        _Pragma("unroll")                                                      \
        for (int k = 0; k < 4; ++k)                                            \
            z[k] = s_stage[wid][sub * 16 + ((c * 4 + k) ^ sub)];               \
        const int t  = (t_);                                                   \
        const int x  = (2 * c + t) & 7;                                        \
        const int tb = t * 32 + c * 8;                                         \
        /* two independent 8-expert cascades (dual-issue friendly) */          \
        float vA1 = -INFINITY, vA2 = -INFINITY, vB1 = -INFINITY, vB2 = -INFINITY; \
        int   iA1 = 0, iA2 = 0, iB1 = 0, iB2 = 0;                              \
        float nA1 = 0.f, nA2 = 0.f, nB1 = 0.f, nB2 = 0.f;                      \
        STEPC(vA1,iA1,nA1,vA2,iA2,nA2, 0, z[0].x, z[0].y);                     \
        STEPC(vB1,iB1,nB1,vB2,iB2,nB2, 4, z[2].x, z[2].y);                     \
        STEPC(vA1,iA1,nA1,vA2,iA2,nA2, 1, z[0].z, z[0].w);                     \
        STEPC(vB1,iB1,nB1,vB2,iB2,nB2, 5, z[2].z, z[2].w);                     \
        STEPC(vA1,iA1,nA1,vA2,iA2,nA2, 2, z[1].x, z[1].y);                     \
        STEPC(vB1,iB1,nB1,vB2,iB2,nB2, 6, z[3].x, z[3].y);                     \
        STEPC(vA1,iA1,nA1,vA2,iA2,nA2, 3, z[1].z, z[1].w);                     \
        STEPC(vB1,iB1,nB1,vB2,iB2,nB2, 7, z[3].z, z[3].w);                     \
        /* in-lane merge: all A-indices < all B-indices (tie -> A) */          \
        float v1, v2, n1, n2; int i1, i2;                                      \
        if (vB1 > vA1) {                                                       \
            v1 = vB1; i1 = iB1; n1 = nB1;                                      \
            const bool s2 = vB2 > vA1;                                         \
            v2 = s2 ? vB2 : vA1; i2 = s2 ? iB2 : iA1; n2 = s2 ? nB2 : nA1;     \
        } else {                                                               \
            v1 = vA1; i1 = iA1; n1 = nA1;                                      \
            const bool s2 = vB1 > vA2;                                         \
            v2 = s2 ? vB1 : vA2; i2 = s2 ? iB1 : iA2; n2 = s2 ? nB1 : nA2;     \
        }                                                                      \
        /* 2 shuffle-merge rounds across the 4 team lanes */                   \
        _Pragma("unroll")                                                      \
        for (int m = 1; m <= 2; m <<= 1) {                                     \
            const float w1 = __shfl_xor(v1, m), w2 = __shfl_xor(v2, m);        \
            const int   j1 = __shfl_xor(i1, m), j2 = __shfl_xor(i2, m);        \
            const float q1 = __shfl_xor(n1, m), q2 = __shfl_xor(n2, m);        \
            const bool aw = (v1 > w1) || (v1 == w1 && i1 < j1);                \
            const float p1 = aw ? v1 : w1, p2 = aw ? v2 : w2;                  \
            const int   pi1 = aw ? i1 : j1, pi2 = aw ? i2 : j2;                \
            const float pn1 = aw ? n1 : q1, pn2 = aw ? n2 : q2;                \
            const float u1 = aw ? w1 : v1;                                     \
            const int   ui1 = aw ? j1 : i1;                                    \
            const float un1 = aw ? q1 : n1;                                    \
            const bool b2 = (p2 > u1) || (p2 == u1 && pi2 < ui1);              \
            v1 = p1;  i1 = pi1; n1 = pn1;                                      \
            v2 = b2 ? p2 : u1;  i2 = b2 ? pi2 : ui1;  n2 = b2 ? pn2 : un1;     \
        }                                                                      \
        /* f32 2-way softmax (selection already fixed) */                      \
        const float e2 = expf(v2 - v1);                                        \
        const float g1 = 1.0f / (1.0f + e2);                                   \
        const float g2 = e2 / (1.0f + e2);                                     \
        const int ia = i1, ib = i2;                                            \
        const int iab = ia | (ib << 8);                                        \
        if (c == 0 && ((rowbase_) + sub) < B) {                                \
            atomicAdd(&s_load[ia], g1);                                        \
            atomicAdd(&s_load[ib], g2);                                        \
        }                                                                      \
        const int gb_ = (rowbase_) * 16;                                       \
        _Pragma("unroll")                                                      \
        for (int j = 0; j < 4; ++j) {                                          \
            const int f  = j * 64 + lane;                                      \
            const int rr = f >> 4;                                             \
            const int p  = f & 15;                                             \
            const int src = rr << 2;                                           \
            const int   siab = __shfl(iab, src);                               \
            const float sg1  = __shfl(g1,  src);                               \
            const float sg2  = __shfl(g2,  src);                               \
            const int sia = siab & 255, sib = siab >> 8;                       \
            const int e0 = p * 4;                                              \
            float4 w;                                                          \
            w.x = (e0 + 0 == sia) ? sg1 : ((e0 + 0 == sib) ? sg2 : 0.f);       \
            w.y = (e0 + 1 == sia) ? sg1 : ((e0 + 1 == sib) ? sg2 : 0.f);       \
            w.z = (e0 + 2 == sia) ? sg1 : ((e0 + 2 == sib) ? sg2 : 0.f);       \
            w.w = (e0 + 3 == sia) ? sg1 : ((e0 + 3 == sib) ? sg2 : 0.f);       \
            const int gidx = gb_ + f;                                          \
            if (gidx < n4) gates4[gidx] = w;                                   \
        }                                                                      \
    }

        PROCHALF(tA, g * RPI,      cur[0], cur[1], cur[2], cur[3])
        PROCHALF(tB, g * RPI + 16, cur[4], cur[5], cur[6], cur[7])

#undef PROCHALF
#undef STEPC
#undef INS2C

        #pragma unroll
        for (int j = 0; j < 8; ++j) cur[j] = nxt[j];
        tA = ntA; tB = ntB;
    }
    __syncthreads();
    if (tid < NE) atomicAdd(&load[tid], s_load[tid]);
}

// ---------------------------------------------------------------------------
extern "C" void kernel_launch(void* const* d_in, const int* in_sizes, int n_in,
                              void* d_out, int out_size, void* d_ws, size_t ws_size,
                              hipStream_t stream) {
    const int*   taskID      = (const int*)  d_in[0];
    const float* embed_table = (const float*)d_in[1];
    const float* expert_keys = (const float*)d_in[2];
    const float* in_proj_w   = (const float*)d_in[3];
    const float* in_proj_b   = (const float*)d_in[4];
    const float* fc_gate_w   = (const float*)d_in[5];
    const float* fc_gate_b   = (const float*)d_in[6];
    const float* fc_noise_w  = (const float*)d_in[7];
    const float* fc_noise_b  = (const float*)d_in[8];
    const float* noise       = (const float*)d_in[9];

    const int B = in_sizes[0];

    float* tab_f = (float*)d_ws;   // 4 KB

    float* gates = (float*)d_out;
    float* load  = gates + (size_t)B * NE;

    precompute_kernel<<<1, BLK, 0, stream>>>(embed_table, expert_keys, in_proj_w, in_proj_b,
                                             fc_gate_w, fc_gate_b, fc_noise_w, fc_noise_b,
                                             tab_f, load);

    router_kernel<<<GRID, BLK, 0, stream>>>(taskID, (const float4*)noise,
                                            (const float4*)tab_f,
                                            (float4*)gates, load, B);
}